// Round 4
// baseline (768.365 us; speedup 1.0000x reference)
//
#include <hip/hip_runtime.h>
#include <math.h>

#define NGENES 978
#define EDIM   301
#define NNODES 10000
#define NEDGES 320000
#define KPAD   992      // 31*32 (K padded for MFMA)
#define NPAD   320      // 5*64  (N padded)
#define MPAD   10112    // 79*128 (M padded)
#define HP     320      // padded h row stride (floats), 1280 B, 16B-aligned

typedef float f4v __attribute__((ext_vector_type(4)));
typedef short s8v __attribute__((ext_vector_type(8)));

// ---------------- bf16 split: v ~= hi + lo (truncation split) ----------------
__device__ __forceinline__ void split_bf16(float v, short& hi, short& lo) {
    unsigned int b = __float_as_uint(v);
    hi = (short)(b >> 16);
    float hif = __uint_as_float(b & 0xFFFF0000u);
    float lof = v - hif;               // exact
    lo = (short)(__float_as_uint(lof) >> 16);
}

// ---------------- prep: init deg/cnt/cur + detect idx dtype ----------------
__global__ void prep_init(const unsigned int* __restrict__ ei, int* flag,
                          float* deg, int* cnt, int* cur) {
    int i = blockIdx.x * blockDim.x + threadIdx.x;
    if (i < NNODES) { deg[i] = 1.0f; cnt[i] = 0; cur[i] = 0; }
    if (blockIdx.x == 0 && threadIdx.x < 64) {
        // int64 edge_index (values < 2^31) => all odd 32-bit words zero
        unsigned int v = ei[2 * threadIdx.x + 1];
        unsigned long long nz = __ballot(v != 0u);
        if (threadIdx.x == 0) *flag = (nz == 0ULL) ? 1 : 0;
    }
}

__device__ __forceinline__ int load_idx(const void* ei, long long i, int is64) {
    return is64 ? (int)((const long long*)ei)[i] : ((const int*)ei)[i];
}

// ---------------- per-edge: deg += w, cnt++ ----------------
__global__ void accum_deg(const void* __restrict__ ei, const float* __restrict__ w,
                          float* deg, int* cnt, const int* __restrict__ flag) {
    int i = blockIdx.x * blockDim.x + threadIdx.x;
    if (i >= NEDGES) return;
    int is64 = *flag;
    int d = load_idx(ei, (long long)NEDGES + i, is64);
    atomicAdd(&deg[d], w[i]);
    atomicAdd(&cnt[d], 1);
}

// ---------------- scan cnt -> base, plus dinv = rsqrt(deg) ----------------
__global__ __launch_bounds__(1024) void scan_dinv(const int* __restrict__ cnt,
                                                  int* __restrict__ base_,
                                                  const float* __restrict__ deg,
                                                  float* __restrict__ dinv) {
    __shared__ int part[1024];
    const int t = threadIdx.x;
    int local[10];
    int s = 0;
    #pragma unroll
    for (int j = 0; j < 10; ++j) {
        int idx = t * 10 + j;
        int v = (idx < NNODES) ? cnt[idx] : 0;
        local[j] = s;
        s += v;
    }
    part[t] = s;
    __syncthreads();
    for (int off = 1; off < 1024; off <<= 1) {
        int v = (t >= off) ? part[t - off] : 0;
        __syncthreads();
        part[t] += v;
        __syncthreads();
    }
    int carry = (t > 0) ? part[t - 1] : 0;
    #pragma unroll
    for (int j = 0; j < 10; ++j) {
        int idx = t * 10 + j;
        if (idx < NNODES) {
            base_[idx] = carry + local[j];
            float d = deg[idx];
            dinv[idx] = (d > 0.0f) ? rsqrtf(d) : 0.0f;
        }
    }
}

// ---------------- bucket fill: (src, norm) pairs grouped by dst ----------------
__global__ void fill_csr(const void* __restrict__ ei, const float* __restrict__ w,
                         const float* __restrict__ dinv, const int* __restrict__ base_,
                         int* cur, int2* __restrict__ ee,
                         const int* __restrict__ flag) {
    int e = blockIdx.x * blockDim.x + threadIdx.x;
    if (e >= NEDGES) return;
    int is64 = *flag;
    int s = load_idx(ei, e, is64);
    int d = load_idx(ei, (long long)NEDGES + e, is64);
    float nrm = dinv[s] * w[e] * dinv[d];
    int pos = base_[d] + atomicAdd(&cur[d], 1);
    ee[pos] = make_int2(s, __float_as_int(nrm));
}

// -------- convert x -> xh/xl [10000][992] and W -> W^T hi/lo [320][992] -----
#define XCH (NNODES * (KPAD / 8))     // 1,240,000 chunks of 8
#define WCH (NPAD * (KPAD / 8))       // 39,680
__global__ void cvt_xw(const float* __restrict__ x, const float* __restrict__ W,
                       short* __restrict__ xh, short* __restrict__ xl,
                       short* __restrict__ wh, short* __restrict__ wl) {
    int idx = blockIdx.x * blockDim.x + threadIdx.x;
    if (idx < XCH) {
        int r = idx / (KPAD / 8);
        int kc = (idx - r * (KPAD / 8)) * 8;
        s8v h8, l8;
        #pragma unroll
        for (int j = 0; j < 8; ++j) {
            int k = kc + j;
            float v = (k < NGENES) ? x[(size_t)r * NGENES + k] : 0.0f;
            short hi, lo;
            split_bf16(v, hi, lo);
            h8[j] = hi; l8[j] = lo;
        }
        *(s8v*)(xh + (size_t)r * KPAD + kc) = h8;
        *(s8v*)(xl + (size_t)r * KPAD + kc) = l8;
    } else if (idx < XCH + WCH) {
        int wi = idx - XCH;
        int n = wi / (KPAD / 8);
        int kc = (wi - n * (KPAD / 8)) * 8;
        s8v h8, l8;
        #pragma unroll
        for (int j = 0; j < 8; ++j) {
            int k = kc + j;
            float v = (n < EDIM && k < NGENES) ? W[(size_t)k * EDIM + n] : 0.0f;
            short hi, lo;
            split_bf16(v, hi, lo);
            h8[j] = hi; l8[j] = lo;
        }
        *(s8v*)(wh + (size_t)n * KPAD + kc) = h8;
        *(s8v*)(wl + (size_t)n * KPAD + kc) = l8;
    }
}

// ---------------- MFMA GEMM: h[N,320] = x @ W (bf16 3-pass split) -----------
// 128x64 block tile, 4 waves (2x2), wave tile 64x32, BK=32.
// LDS rows padded to 40 shorts (80 B) -> low bank aliasing on b128 reads.
__global__ __launch_bounds__(256) void gemm_bf16(const short* __restrict__ xh,
                                                 const short* __restrict__ xl,
                                                 const short* __restrict__ wh,
                                                 const short* __restrict__ wl,
                                                 float* __restrict__ h) {
    __shared__ short Ah[128 * 40], Al[128 * 40], Bh[64 * 40], Bl[64 * 40];
    const int tid  = threadIdx.x;
    const int lane = tid & 63;
    const int w    = tid >> 6;
    const int wm   = (w >> 1) * 64;
    const int wn   = (w & 1) * 32;
    const int bm   = blockIdx.y * 128;
    const int bn   = blockIdx.x * 64;
    const int l15  = lane & 15;
    const int g8   = (lane >> 4) * 8;    // k offset (shorts) of this lane group

    f4v acc[4][2] = {};

    const int arow0 = tid >> 2;          // 0..63
    const int aslot = (tid & 3) * 8;     // 0,8,16,24

    for (int ks = 0; ks < KPAD / 32; ++ks) {
        const int k0 = ks * 32;
        #pragma unroll
        for (int q = 0; q < 2; ++q) {
            const int row = q * 64 + arow0;
            const size_t goff = (size_t)(bm + row) * KPAD + k0 + aslot;
            s8v vh = *(const s8v*)(xh + goff);
            s8v vl = *(const s8v*)(xl + goff);
            *(s8v*)&Ah[row * 40 + aslot] = vh;
            *(s8v*)&Al[row * 40 + aslot] = vl;
        }
        {
            const int row = tid >> 2;    // 0..63
            const size_t goff = (size_t)(bn + row) * KPAD + k0 + aslot;
            s8v vh = *(const s8v*)(wh + goff);
            s8v vl = *(const s8v*)(wl + goff);
            *(s8v*)&Bh[row * 40 + aslot] = vh;
            *(s8v*)&Bl[row * 40 + aslot] = vl;
        }
        __syncthreads();
        s8v ah[4], al[4], bh[2], bl[2];
        #pragma unroll
        for (int fn = 0; fn < 2; ++fn) {
            const int r = wn + fn * 16 + l15;
            bh[fn] = *(const s8v*)&Bh[r * 40 + g8];
            bl[fn] = *(const s8v*)&Bl[r * 40 + g8];
        }
        #pragma unroll
        for (int fm = 0; fm < 4; ++fm) {
            const int r = wm + fm * 16 + l15;
            ah[fm] = *(const s8v*)&Ah[r * 40 + g8];
            al[fm] = *(const s8v*)&Al[r * 40 + g8];
        }
        #pragma unroll
        for (int fm = 0; fm < 4; ++fm)
            #pragma unroll
            for (int fn = 0; fn < 2; ++fn) {
                acc[fm][fn] = __builtin_amdgcn_mfma_f32_16x16x32_bf16(ah[fm], bh[fn], acc[fm][fn], 0, 0, 0);
                acc[fm][fn] = __builtin_amdgcn_mfma_f32_16x16x32_bf16(ah[fm], bl[fn], acc[fm][fn], 0, 0, 0);
                acc[fm][fn] = __builtin_amdgcn_mfma_f32_16x16x32_bf16(al[fm], bh[fn], acc[fm][fn], 0, 0, 0);
            }
        __syncthreads();
    }
    // C write: D col = lane&15 (n), row = (lane>>4)*4 + reg (m); pad cols are
    // exact zeros (B zero-padded), so write all cols < 320.
    const int mrb = (lane >> 4) * 4;
    #pragma unroll
    for (int fm = 0; fm < 4; ++fm)
        #pragma unroll
        for (int fn = 0; fn < 2; ++fn) {
            const int col = bn + wn + fn * 16 + l15;
            #pragma unroll
            for (int r = 0; r < 4; ++r) {
                const int row = bm + wm + fm * 16 + mrb + r;
                if (row < NNODES) h[(size_t)row * HP + col] = acc[fm][fn][r];
            }
        }
}

// ------- fused gather + self-loop + bias + relu + coalesced broadcast -------
// One block (320 thr = 4 groups x 80) per dst node. Group g handles edge
// (e0 + g); thread owns one float4 of the 320-float padded row.
__global__ __launch_bounds__(320) void gather_out(const float* __restrict__ h,
                                                  const float* __restrict__ dinv,
                                                  const float* __restrict__ bias,
                                                  const int2* __restrict__ ee,
                                                  const int* __restrict__ base_,
                                                  const int* __restrict__ cnt,
                                                  float4* __restrict__ out) {
    __shared__ float red[4][HP];
    __shared__ float row[HP];
    const int n  = blockIdx.x;
    const int t  = threadIdx.x;
    const int g  = t / 80;
    const int gt = t - g * 80;          // 0..79, owns cols 4*gt..4*gt+3

    const int b0 = base_[n];
    const int cn = cnt[n];
    float4 acc = make_float4(0.f, 0.f, 0.f, 0.f);
    for (int e = g; e < cn; e += 4) {
        int2 p = ee[b0 + e];            // wave-broadcast load
        float nr = __int_as_float(p.y);
        float4 v = *(const float4*)(h + (size_t)p.x * HP + 4 * gt);
        acc.x = fmaf(nr, v.x, acc.x);
        acc.y = fmaf(nr, v.y, acc.y);
        acc.z = fmaf(nr, v.z, acc.z);
        acc.w = fmaf(nr, v.w, acc.w);
    }
    *(float4*)&red[g][4 * gt] = acc;
    __syncthreads();
    if (t < HP) {
        float dn = dinv[n];
        float s = red[0][t] + red[1][t] + red[2][t] + red[3][t]
                + h[(size_t)n * HP + t] * (dn * dn)
                + ((t < EDIM) ? bias[t] : 0.0f);
        row[t] = fmaxf(s, 0.0f);
    }
    __syncthreads();

    // out[n][head][c][0..11] = 4 heads x 903 float4; coalesced
    float4* o = out + (size_t)n * 4 * 903;
    #pragma unroll
    for (int q = 0; q < 3; ++q) {
        int p = q * 320 + t;
        if (p < 903) {
            const float v = row[p / 3];
            const float4 vv = make_float4(v, v, v, v);
            o[p] = vv; o[903 + p] = vv; o[1806 + p] = vv; o[2709 + p] = vv;
        }
    }
}

// ---------------- launch ----------------
extern "C" void kernel_launch(void* const* d_in, const int* in_sizes, int n_in,
                              void* d_out, int out_size, void* d_ws, size_t ws_size,
                              hipStream_t stream) {
    const float* x  = (const float*)d_in[0];
    const void*  ei = d_in[1];
    const float* ew = (const float*)d_in[2];
    const float* W  = (const float*)d_in[3];
    const float* b  = (const float*)d_in[4];

    char* p = (char*)d_ws;
    float* deg  = (float*)p;                 p += 40960;
    float* dinv = (float*)p;                 p += 40960;
    int*   cnt  = (int*)p;                   p += 40960;
    int*   base_= (int*)p;                   p += 40960;
    int*   cur  = (int*)p;                   p += 40960;
    int*   flag = (int*)p;                   p += 256;
    int2*  ee   = (int2*)p;                  p += (size_t)NEDGES * 8;
    float* h    = (float*)p;                 p += (size_t)NNODES * HP * 4;
    short* xh   = (short*)p;                 p += (size_t)MPAD * KPAD * 2;
    short* xl   = (short*)p;                 p += (size_t)MPAD * KPAD * 2;
    short* wh   = (short*)p;                 p += (size_t)NPAD * KPAD * 2;
    short* wl   = (short*)p;                 p += (size_t)NPAD * KPAD * 2;
    // total ~57 MB

    prep_init<<<40, 256, 0, stream>>>((const unsigned int*)ei, flag, deg, cnt, cur);
    accum_deg<<<(NEDGES + 255) / 256, 256, 0, stream>>>(ei, ew, deg, cnt, flag);
    scan_dinv<<<1, 1024, 0, stream>>>(cnt, base_, deg, dinv);
    fill_csr<<<(NEDGES + 255) / 256, 256, 0, stream>>>(ei, ew, dinv, base_, cur, ee, flag);

    cvt_xw<<<(XCH + WCH + 255) / 256, 256, 0, stream>>>(x, W, xh, xl, wh, wl);

    dim3 ggrid(NPAD / 64, MPAD / 128);
    gemm_bf16<<<ggrid, 256, 0, stream>>>(xh, xl, wh, wl, h);

    gather_out<<<NNODES, 320, 0, stream>>>(h, dinv, b, ee, base_, cnt, (float4*)d_out);
    (void)in_sizes; (void)n_in; (void)out_size; (void)ws_size;
}

// Round 5
// 729.701 us; speedup vs baseline: 1.0530x; 1.0530x over previous
//
#include <hip/hip_runtime.h>
#include <math.h>

#define NGENES 978
#define EDIM   301
#define NNODES 10000
#define NEDGES 320000
#define KPAD   992      // 31*32 (K padded for MFMA)
#define NPAD   320      // 5*64  (N padded)
#define MPAD   10112    // 79*128 (M padded)
#define HP     320      // padded h row stride (floats)
#define ELLS   128      // ELL slots per node (P(deg>128) ~ 1e-40 for Poisson(32))

typedef float f4v __attribute__((ext_vector_type(4)));
typedef short s8v __attribute__((ext_vector_type(8)));

// ---------------- bf16 split: v ~= hi + lo (truncation split) ----------------
__device__ __forceinline__ void split_bf16(float v, short& hi, short& lo) {
    unsigned int b = __float_as_uint(v);
    hi = (short)(b >> 16);
    float hif = __uint_as_float(b & 0xFFFF0000u);
    float lof = v - hif;               // exact
    lo = (short)(__float_as_uint(lof) >> 16);
}

// ---------------- prep: zero cur + detect idx dtype ----------------
__global__ void prep_init(const unsigned int* __restrict__ ei, int* flag, int* cur) {
    int i = blockIdx.x * blockDim.x + threadIdx.x;
    if (i < NNODES) cur[i] = 0;
    if (blockIdx.x == 0 && threadIdx.x < 64) {
        // int64 edge_index (values < 2^31) => all odd 32-bit words zero
        unsigned int v = ei[2 * threadIdx.x + 1];
        unsigned long long nz = __ballot(v != 0u);
        if (threadIdx.x == 0) *flag = (nz == 0ULL) ? 1 : 0;
    }
}

__device__ __forceinline__ int load_idx(const void* ei, long long i, int is64) {
    return is64 ? (int)((const long long*)ei)[i] : ((const int*)ei)[i];
}

// ---------------- single-pass ELL build: ell[d][slot] = (src, w) ------------
__global__ void fill_ell(const void* __restrict__ ei, const float* __restrict__ w,
                         int* cur, int2* __restrict__ ell,
                         const int* __restrict__ flag) {
    int e = blockIdx.x * blockDim.x + threadIdx.x;
    if (e >= NEDGES) return;
    int is64 = *flag;
    int s = load_idx(ei, e, is64);
    int d = load_idx(ei, (long long)NEDGES + e, is64);
    int slot = atomicAdd(&cur[d], 1);
    if (slot < ELLS) ell[(size_t)d * ELLS + slot] = make_int2(s, __float_as_int(w[e]));
}

// ---------------- deg/dinv from ELL: wave per node ----------------
__global__ __launch_bounds__(256) void deg_dinv(const int2* __restrict__ ell,
                                                const int* __restrict__ cur,
                                                float* __restrict__ dinv) {
    int n = (blockIdx.x * blockDim.x + threadIdx.x) >> 6;
    int lane = threadIdx.x & 63;
    if (n >= NNODES) return;
    int cnt = min(cur[n], ELLS);
    float s = 0.0f;
    for (int l = lane; l < cnt; l += 64)
        s += __int_as_float(ell[(size_t)n * ELLS + l].y);
    #pragma unroll
    for (int off = 32; off; off >>= 1) s += __shfl_xor(s, off);
    if (lane == 0) dinv[n] = rsqrtf(1.0f + s);   // deg = 1 (self-loop) + sum(w)
}

// -------- convert x -> xh/xl [10000][992] and W -> W^T hi/lo [320][992] -----
#define XCH (NNODES * (KPAD / 8))     // 1,240,000 chunks of 8
#define WCH (NPAD * (KPAD / 8))       // 39,680
__global__ void cvt_xw(const float* __restrict__ x, const float* __restrict__ W,
                       short* __restrict__ xh, short* __restrict__ xl,
                       short* __restrict__ wh, short* __restrict__ wl) {
    int idx = blockIdx.x * blockDim.x + threadIdx.x;
    if (idx < XCH) {
        int r = idx / (KPAD / 8);
        int kc = (idx - r * (KPAD / 8)) * 8;
        s8v h8, l8;
        #pragma unroll
        for (int j = 0; j < 8; ++j) {
            int k = kc + j;
            float v = (k < NGENES) ? x[(size_t)r * NGENES + k] : 0.0f;
            short hi, lo;
            split_bf16(v, hi, lo);
            h8[j] = hi; l8[j] = lo;
        }
        *(s8v*)(xh + (size_t)r * KPAD + kc) = h8;
        *(s8v*)(xl + (size_t)r * KPAD + kc) = l8;
    } else if (idx < XCH + WCH) {
        int wi = idx - XCH;
        int n = wi / (KPAD / 8);
        int kc = (wi - n * (KPAD / 8)) * 8;
        s8v h8, l8;
        #pragma unroll
        for (int j = 0; j < 8; ++j) {
            int k = kc + j;
            float v = (n < EDIM && k < NGENES) ? W[(size_t)k * EDIM + n] : 0.0f;
            short hi, lo;
            split_bf16(v, hi, lo);
            h8[j] = hi; l8[j] = lo;
        }
        *(s8v*)(wh + (size_t)n * KPAD + kc) = h8;
        *(s8v*)(wl + (size_t)n * KPAD + kc) = l8;
    }
}

// ---------------- MFMA GEMM: h[N,320] = x @ W (bf16 3-pass split) -----------
// 128x64 block tile, 4 waves (2x2), wave tile 64x32, BK=32.
__global__ __launch_bounds__(256) void gemm_bf16(const short* __restrict__ xh,
                                                 const short* __restrict__ xl,
                                                 const short* __restrict__ wh,
                                                 const short* __restrict__ wl,
                                                 float* __restrict__ h) {
    __shared__ short Ah[128 * 40], Al[128 * 40], Bh[64 * 40], Bl[64 * 40];
    const int tid  = threadIdx.x;
    const int lane = tid & 63;
    const int w    = tid >> 6;
    const int wm   = (w >> 1) * 64;
    const int wn   = (w & 1) * 32;
    const int bm   = blockIdx.y * 128;
    const int bn   = blockIdx.x * 64;
    const int l15  = lane & 15;
    const int g8   = (lane >> 4) * 8;

    f4v acc[4][2] = {};

    const int arow0 = tid >> 2;
    const int aslot = (tid & 3) * 8;

    for (int ks = 0; ks < KPAD / 32; ++ks) {
        const int k0 = ks * 32;
        #pragma unroll
        for (int q = 0; q < 2; ++q) {
            const int row = q * 64 + arow0;
            const size_t goff = (size_t)(bm + row) * KPAD + k0 + aslot;
            s8v vh = *(const s8v*)(xh + goff);
            s8v vl = *(const s8v*)(xl + goff);
            *(s8v*)&Ah[row * 40 + aslot] = vh;
            *(s8v*)&Al[row * 40 + aslot] = vl;
        }
        {
            const int row = tid >> 2;
            const size_t goff = (size_t)(bn + row) * KPAD + k0 + aslot;
            s8v vh = *(const s8v*)(wh + goff);
            s8v vl = *(const s8v*)(wl + goff);
            *(s8v*)&Bh[row * 40 + aslot] = vh;
            *(s8v*)&Bl[row * 40 + aslot] = vl;
        }
        __syncthreads();
        s8v ah[4], al[4], bh[2], bl[2];
        #pragma unroll
        for (int fn = 0; fn < 2; ++fn) {
            const int r = wn + fn * 16 + l15;
            bh[fn] = *(const s8v*)&Bh[r * 40 + g8];
            bl[fn] = *(const s8v*)&Bl[r * 40 + g8];
        }
        #pragma unroll
        for (int fm = 0; fm < 4; ++fm) {
            const int r = wm + fm * 16 + l15;
            ah[fm] = *(const s8v*)&Ah[r * 40 + g8];
            al[fm] = *(const s8v*)&Al[r * 40 + g8];
        }
        #pragma unroll
        for (int fm = 0; fm < 4; ++fm)
            #pragma unroll
            for (int fn = 0; fn < 2; ++fn) {
                acc[fm][fn] = __builtin_amdgcn_mfma_f32_16x16x32_bf16(ah[fm], bh[fn], acc[fm][fn], 0, 0, 0);
                acc[fm][fn] = __builtin_amdgcn_mfma_f32_16x16x32_bf16(ah[fm], bl[fn], acc[fm][fn], 0, 0, 0);
                acc[fm][fn] = __builtin_amdgcn_mfma_f32_16x16x32_bf16(al[fm], bh[fn], acc[fm][fn], 0, 0, 0);
            }
        __syncthreads();
    }
    const int mrb = (lane >> 4) * 4;
    #pragma unroll
    for (int fm = 0; fm < 4; ++fm)
        #pragma unroll
        for (int fn = 0; fn < 2; ++fn) {
            const int col = bn + wn + fn * 16 + l15;
            #pragma unroll
            for (int r = 0; r < 4; ++r) {
                const int row = bm + wm + fm * 16 + mrb + r;
                if (row < NNODES) h[(size_t)row * HP + col] = acc[fm][fn][r];
            }
        }
}

// ------- fused gather + self-loop + bias + relu + coalesced broadcast -------
// One block (320 threads) per dst node; thread t owns column t. 4-edge ILP.
// norm = (w*dinv[src]) per edge; dinv[n] factored out of the sum.
__global__ __launch_bounds__(320) void gather_out(const float* __restrict__ h,
                                                  const float* __restrict__ dinv,
                                                  const float* __restrict__ bias,
                                                  const int2* __restrict__ ell,
                                                  const int* __restrict__ cur,
                                                  f4v* __restrict__ out) {
    __shared__ float row[HP];
    const int n = blockIdx.x;
    const int t = threadIdx.x;
    const int cnt = min(cur[n], ELLS);
    const int2* en = ell + (size_t)n * ELLS;

    float acc = 0.0f;
    int e = 0;
    for (; e + 4 <= cnt; e += 4) {
        int2 p0 = en[e], p1 = en[e + 1], p2 = en[e + 2], p3 = en[e + 3];
        float w0 = __int_as_float(p0.y) * dinv[p0.x];
        float w1 = __int_as_float(p1.y) * dinv[p1.x];
        float w2 = __int_as_float(p2.y) * dinv[p2.x];
        float w3 = __int_as_float(p3.y) * dinv[p3.x];
        float v0 = h[(size_t)p0.x * HP + t];
        float v1 = h[(size_t)p1.x * HP + t];
        float v2 = h[(size_t)p2.x * HP + t];
        float v3 = h[(size_t)p3.x * HP + t];
        acc = fmaf(w0, v0, acc); acc = fmaf(w1, v1, acc);
        acc = fmaf(w2, v2, acc); acc = fmaf(w3, v3, acc);
    }
    for (; e < cnt; ++e) {
        int2 p = en[e];
        acc = fmaf(__int_as_float(p.y) * dinv[p.x], h[(size_t)p.x * HP + t], acc);
    }

    const float dn = dinv[n];
    float v = acc * dn + h[(size_t)n * HP + t] * (dn * dn)
            + ((t < EDIM) ? bias[t] : 0.0f);
    row[t] = fmaxf(v, 0.0f);
    __syncthreads();

    // out[n][head][c][0..11] = 4 heads x 903 float4; coalesced, non-temporal
    f4v* o = out + (size_t)n * 4 * 903;
    #pragma unroll
    for (int q = 0; q < 3; ++q) {
        int p = q * 320 + t;
        if (p < 903) {
            const float vv = row[p / 3];
            f4v v4 = {vv, vv, vv, vv};
            __builtin_nontemporal_store(v4, &o[p]);
            __builtin_nontemporal_store(v4, &o[903 + p]);
            __builtin_nontemporal_store(v4, &o[1806 + p]);
            __builtin_nontemporal_store(v4, &o[2709 + p]);
        }
    }
}

// ---------------- launch ----------------
extern "C" void kernel_launch(void* const* d_in, const int* in_sizes, int n_in,
                              void* d_out, int out_size, void* d_ws, size_t ws_size,
                              hipStream_t stream) {
    const float* x  = (const float*)d_in[0];
    const void*  ei = d_in[1];
    const float* ew = (const float*)d_in[2];
    const float* W  = (const float*)d_in[3];
    const float* b  = (const float*)d_in[4];

    char* p = (char*)d_ws;
    int*   cur  = (int*)p;                   p += 40960;
    float* dinv = (float*)p;                 p += 40960;
    int*   flag = (int*)p;                   p += 256;
    int2*  ell  = (int2*)p;                  p += (size_t)NNODES * ELLS * 8;  // 10.24 MB
    float* h    = (float*)p;                 p += (size_t)NNODES * HP * 4;    // 12.8 MB
    short* xh   = (short*)p;                 p += (size_t)MPAD * KPAD * 2;
    short* xl   = (short*)p;                 p += (size_t)MPAD * KPAD * 2;
    short* wh   = (short*)p;                 p += (size_t)NPAD * KPAD * 2;
    short* wl   = (short*)p;                 p += (size_t)NPAD * KPAD * 2;
    // total ~64 MB

    prep_init<<<40, 256, 0, stream>>>((const unsigned int*)ei, flag, cur);
    fill_ell<<<(NEDGES + 255) / 256, 256, 0, stream>>>(ei, ew, cur, ell, flag);
    deg_dinv<<<(NNODES * 64 + 255) / 256, 256, 0, stream>>>(ell, cur, dinv);

    cvt_xw<<<(XCH + WCH + 255) / 256, 256, 0, stream>>>(x, W, xh, xl, wh, wl);

    dim3 ggrid(NPAD / 64, MPAD / 128);
    gemm_bf16<<<ggrid, 256, 0, stream>>>(xh, xl, wh, wl, h);

    gather_out<<<NNODES, 320, 0, stream>>>(h, dinv, b, ell, cur, (f4v*)d_out);
    (void)in_sizes; (void)n_in; (void)out_size; (void)ws_size;
}